// Round 8
// baseline (217.040 us; speedup 1.0000x reference)
//
#include <hip/hip_runtime.h>

#define BATCH 4
#define SEQ   4096
#define CDIM  1024
#define DDIM  64
#define NROW  (BATCH * SEQ)   // 16384
#define NSPL  8               // attn key-split
#define SEG   (NROW * DDIM)   // 1M elements per q/k/v buffer

typedef _Float16 f16;
typedef _Float16 f16x8 __attribute__((ext_vector_type(8)));
typedef _Float16 f16x4 __attribute__((ext_vector_type(4)));
typedef __fp16   h16x2 __attribute__((ext_vector_type(2)));  // cvt_pkrtz return type
typedef float    f32x4 __attribute__((ext_vector_type(4)));

#define MFMA32(a, b, c) __builtin_amdgcn_mfma_f32_16x16x32_f16((a), (b), (c), 0, 0, 0)
#define MFMA16(a, b, c) __builtin_amdgcn_mfma_f32_16x16x16f16((a), (b), (c), 0, 0, 0)

// async global->LDS DMA, 16 B per lane; LDS dest = wave-uniform base + lane*16
#define GLDS(g, l)                                                            \
  __builtin_amdgcn_global_load_lds((const __attribute__((address_space(1))) void*)(g), \
                                   (__attribute__((address_space(3))) void*)(l), 16, 0, 0)

// scores = (q·k)*8 (the /scale bug); softmax in exp2 domain => fold 8*log2(e) into q
#define QSCALE 11.5415603f

__device__ inline f16x8 cvt8(f32x4 a, f32x4 b) {
  h16x2 p0 = __builtin_amdgcn_cvt_pkrtz(a[0], a[1]);
  h16x2 p1 = __builtin_amdgcn_cvt_pkrtz(a[2], a[3]);
  h16x2 p2 = __builtin_amdgcn_cvt_pkrtz(b[0], b[1]);
  h16x2 p3 = __builtin_amdgcn_cvt_pkrtz(b[2], b[3]);
  f16x8 r;
  r[0] = p0[0]; r[1] = p0[1]; r[2] = p1[0]; r[3] = p1[1];
  r[4] = p2[0]; r[5] = p2[1]; r[6] = p3[0]; r[7] = p3[1];
  return r;
}

__device__ inline f16x4 cvt4(float a, float b, float c, float d) {
  h16x2 lo = __builtin_amdgcn_cvt_pkrtz(a, b);
  h16x2 hi = __builtin_amdgcn_cvt_pkrtz(c, d);
  f16x4 r;
  r[0] = lo[0]; r[1] = lo[1]; r[2] = hi[0]; r[3] = hi[1];
  return r;
}

// ---------------- W prep: fp32 -> f16, mt-major fragment order ---------------
// wf2 slot s = mt*32 + ck (mt = mat*4+tile 0..11, ck = 32-ch chunk 0..31),
// 512 f16 per slot. Lane l of slot s holds B-frag bytes l*16:
// W[tile*16+n][ck*32+quad*8+j]. mt-major => per-mt W stream is contiguous 32KB.
__global__ __launch_bounds__(256) void prep_w_kernel(const float* __restrict__ Wq,
                                                     const float* __restrict__ Wk,
                                                     const float* __restrict__ Wv,
                                                     f16* __restrict__ wf2) {
  const int t = blockIdx.x * 256 + threadIdx.x;  // 96 blocks -> 24576 threads
  const int lane = t & 63;
  const int s = t >> 6;                // 0..383
  const int mt = s >> 5, ck = s & 31;
  const int mat = mt >> 2, tile = mt & 3;
  const int n = lane & 15, quad = lane >> 4;
  const float* W = (mat == 0) ? Wq : (mat == 1) ? Wk : Wv;
  const float* src = W + (size_t)(tile * 16 + n) * CDIM + ck * 32 + quad * 8;
  const f32x4 a = *(const f32x4*)src;
  const f32x4 b = *(const f32x4*)(src + 4);
  *(f16x8*)(wf2 + (size_t)t * 8) = cvt8(a, b);
}

// ---------------- fused QKV projection: DMA-staged x, deep pipeline ----------
// (unchanged from round 7 -- this is a MEASUREMENT round; see attn launch)
__global__ __launch_bounds__(256, 4) void proj_kernel(const float* __restrict__ x,
                                                      const f16* __restrict__ wf2,
                                                      const float* __restrict__ bq,
                                                      const float* __restrict__ bk,
                                                      const float* __restrict__ bv,
                                                      f16* __restrict__ qs,
                                                      f16* __restrict__ ks,
                                                      f16* __restrict__ vc) {
  __shared__ __attribute__((aligned(16))) char lx[3 * 8192];  // 3 bufs x 16rows x 512B swz
  const int tid = threadIdx.x, lane = tid & 63, w = tid >> 6;  // w 0..3
  const int n = lane & 15, quad = lane >> 4;
  const int rowbase = blockIdx.x * 16;
  const int mtb = 3 * w;

  // DMA sources: wave w instr j covers rows 2*(2w+j)..+1, LDS pos p = lane&31.
  // Source pre-swizzle: 16B chunk c = p ^ r  (involution; read undoes with ^n).
  const float* xsrc[2];
#pragma unroll
  for (int j = 0; j < 2; ++j) {
    const int id = 2 * w + j;
    const int r = id * 2 + (lane >> 5);
    const int c = (lane & 31) ^ r;
    xsrc[j] = x + (size_t)(rowbase + r) * CDIM + c * 4;
  }

  auto issue = [&](int ck, int bufi) {
    char* base = &lx[bufi * 8192];
#pragma unroll
    for (int j = 0; j < 2; ++j)
      GLDS(xsrc[j] + ck * 128, base + (2 * w + j) * 1024);
  };

  const f16* wl = wf2 + (size_t)mtb * 16384 + lane * 8;  // + (ck*4+kk)*512

  f32x4 acc[3];
#pragma unroll
  for (int i = 0; i < 3; ++i) acc[i] = (f32x4){0.f, 0.f, 0.f, 0.f};

  issue(0, 0);
  issue(1, 1);
  for (int ck = 0; ck < 8; ++ck) {
    const int bufi = ck % 3;
    if (ck + 2 < 8) issue(ck + 2, (ck + 2) % 3);
    // wait for THIS chunk's 2 GLDS only; newer chunks stay in flight
    if (ck + 2 < 8)      asm volatile("s_waitcnt vmcnt(4)" ::: "memory");
    else if (ck + 1 < 8) asm volatile("s_waitcnt vmcnt(2)" ::: "memory");
    else                 asm volatile("s_waitcnt vmcnt(0)" ::: "memory");
    __builtin_amdgcn_s_barrier();         // whole tile ck is now in LDS
    __builtin_amdgcn_sched_barrier(0);
    const char* xb = &lx[bufi * 8192] + n * 512;
#pragma unroll
    for (int kk = 0; kk < 4; ++kk) {
      const int c1 = kk * 8 + quad * 2;
      const f32x4 xa = *(const f32x4*)(xb + ((c1 ^ n) << 4));
      const f32x4 xc = *(const f32x4*)(xb + (((c1 + 1) ^ n) << 4));
      const f16x8 af = cvt8(xa, xc);
      const f16* wq = wl + (size_t)(ck * 4 + kk) * 512;
      const f16x8 w0 = *(const f16x8*)(wq);
      const f16x8 w1 = *(const f16x8*)(wq + 16384);
      const f16x8 w2 = *(const f16x8*)(wq + 32768);
      acc[0] = MFMA32(af, w0, acc[0]);
      acc[1] = MFMA32(af, w1, acc[1]);
      acc[2] = MFMA32(af, w2, acc[2]);
    }
    __builtin_amdgcn_s_barrier();         // reads done before buf refill
  }

  // epilogue: bias + final layouts (q*QSCALE, k swizzled, v tiles)
  const int r0 = rowbase + quad * 4;
#pragma unroll
  for (int i2 = 0; i2 < 3; ++i2) {
    const int mt = mtb + i2;
    const int mat = mt >> 2, tile = mt & 3;
    const int d = tile * 16 + n;  // d&15 == n
    const f32x4 aa = acc[i2];
    if (mat == 0) {
      const float bi = bq[d];
#pragma unroll
      for (int r = 0; r < 4; ++r)
        qs[(size_t)(r0 + r) * DDIM + d] = (f16)((aa[r] + bi) * QSCALE);
    } else if (mat == 1) {
      const float bi = bk[d];
#pragma unroll
      for (int r = 0; r < 4; ++r) {
        const int tt = r0 + r;
        const int col = ((((d >> 3) ^ (tt & 7)) << 3) | (d & 7));
        ks[(size_t)tt * DDIM + col] = (f16)(aa[r] + bi);
      }
    } else {
      const float bi = bv[d];
      const int bb = r0 >> 12;
      const int tl = r0 & (SEQ - 1);
      const int ck2 = tl >> 6;
      const int bsw = (((tl & 63) >> 2) ^ n) << 2;
      *(f16x4*)(vc + ((size_t)(bb * 64 + ck2) * 64 + d) * 64 + bsw) =
          cvt4(aa[0] + bi, aa[1] + bi, aa[2] + bi, aa[3] + bi);
    }
  }
}

// ---------------- flash attention: deep-pipelined DMA staging ----------------
// (unchanged from round 7; launched 3x this round -- idempotent -- so that
// dur_total reveals attn's true duration: attn = (dur - 155.1 - ~2.5)/2.)
template <int NSPLIT>
__global__ __launch_bounds__(256, 3) void attn_kernel(const f16* __restrict__ qs,
                                                      const f16* __restrict__ ks,
                                                      const f16* __restrict__ vc,
                                                      float* __restrict__ outp,
                                                      f16* __restrict__ pacc,
                                                      float* __restrict__ pm,
                                                      float* __restrict__ pl) {
  __shared__ __attribute__((aligned(16))) f16 lk[3 * 4096];  // [buf][key][64 d swz]
  __shared__ __attribute__((aligned(16))) f16 lv[3 * 4096];  // [buf][d][64 key swz]
  const int tid = threadIdx.x, lane = tid & 63, w = tid >> 6;
  const int n = lane & 15, quad = lane >> 4;
  const int split = blockIdx.x % NSPLIT;
  const int rowblk = blockIdx.x / NSPLIT;
  const int row0 = rowblk * 128 + w * 32;
  const int bb = row0 >> 12;
  const int kbase = split * (SEQ / NSPLIT);
  const int kc0 = kbase >> 6;
  const int NC = SEQ / NSPLIT / 64;

  const f16* ksb = ks + (size_t)bb * SEQ * DDIM;
  const f16* vcb = vc + (size_t)bb * 64 * 4096;

  auto issue = [&](int c, int bufi) {
#pragma unroll
    for (int i = 0; i < 2; ++i) {
      const int id = 2 * w + i;
      GLDS(ksb + (size_t)(kbase + c * 64) * 64 + id * 512 + lane * 8,
           &lk[bufi * 4096 + id * 512]);
      GLDS(vcb + (size_t)(kc0 + c) * 4096 + id * 512 + lane * 8,
           &lv[bufi * 4096 + id * 512]);
    }
  };

  // persistent Q B-fragments (16x16x32): B[k=d=quad*8+j][col=q=n]
  f16x8 qf[2][2];
#pragma unroll
  for (int g = 0; g < 2; ++g)
#pragma unroll
    for (int hh = 0; hh < 2; ++hh)
      qf[g][hh] = *(const f16x8*)(qs + (size_t)(row0 + g * 16 + n) * DDIM + hh * 32 + quad * 8);

  // swizzle read offsets (per-lane constants)
  const int kswz = (quad ^ (n & 7)) << 3;          // klo block; khi = kswz ^ 32
  int vswz[4];
#pragma unroll
  for (int st = 0; st < 4; ++st) vswz[st] = ((((st << 2) | quad) ^ n) << 2);

  f32x4 acc[2][4];
  float m[2] = {-1e30f, -1e30f}, ll[2] = {0.f, 0.f};
#pragma unroll
  for (int g = 0; g < 2; ++g)
#pragma unroll
    for (int t = 0; t < 4; ++t) acc[g][t] = (f32x4){0.f, 0.f, 0.f, 0.f};

  issue(0, 0);
  issue(1, 1);
  for (int c = 0; c < NC; ++c) {
    const int bufi = c % 3;
    if (c + 2 < NC) issue(c + 2, (c + 2) % 3);
    // wait for THIS chunk's 4 GLDS only; newer chunks stay in flight
    if (c + 2 < NC)      asm volatile("s_waitcnt vmcnt(8)" ::: "memory");
    else if (c + 1 < NC) asm volatile("s_waitcnt vmcnt(4)" ::: "memory");
    else                 asm volatile("s_waitcnt vmcnt(0)" ::: "memory");
    __builtin_amdgcn_s_barrier();         // whole K/V tile c is now in LDS
    __builtin_amdgcn_sched_barrier(0);

    // S' = K·Q^T
    f32x4 s[2][4];
#pragma unroll
    for (int st = 0; st < 4; ++st) {
      const f16* lkr = &lk[bufi * 4096 + (st * 16 + n) * 64];
      const f16x8 klo = *(const f16x8*)(lkr + kswz);
      const f16x8 khi = *(const f16x8*)(lkr + (kswz ^ 32));
#pragma unroll
      for (int g = 0; g < 2; ++g) {
        f32x4 z = (f32x4){0.f, 0.f, 0.f, 0.f};
        z = MFMA32(klo, qf[g][0], z);
        s[g][st] = MFMA32(khi, qf[g][1], z);
      }
    }

    // per-lane online softmax; P packed directly as 16x16x16 B-fragments
    f16x4 pq[2][4];
#pragma unroll
    for (int g = 0; g < 2; ++g) {
      f32x4 mx;
#pragma unroll
      for (int r = 0; r < 4; ++r)
        mx[r] = fmaxf(fmaxf(s[g][0][r], s[g][1][r]), fmaxf(s[g][2][r], s[g][3][r]));
      float mloc = fmaxf(fmaxf(mx[0], mx[1]), fmaxf(mx[2], mx[3]));
      mloc = fmaxf(mloc, __shfl_xor(mloc, 16));
      mloc = fmaxf(mloc, __shfl_xor(mloc, 32));
      const float mnew = fmaxf(m[g], mloc);
      const float alpha = __builtin_amdgcn_exp2f(m[g] - mnew);
      m[g] = mnew;
      float psum = 0.f;
#pragma unroll
      for (int st = 0; st < 4; ++st) {
        f32x4 p;
#pragma unroll
        for (int r = 0; r < 4; ++r) p[r] = __builtin_amdgcn_exp2f(s[g][st][r] - mnew);
        psum += (p[0] + p[1]) + (p[2] + p[3]);
        pq[g][st] = cvt4(p[0], p[1], p[2], p[3]);
      }
      ll[g] = ll[g] * alpha + psum;
#pragma unroll
      for (int t = 0; t < 4; ++t) acc[g][t] *= alpha;
    }

    // O^T += V^T·P^T : A = V^T frag [m=d][k=key quad*4+j] (swizzled LDS read)
#pragma unroll
    for (int dt = 0; dt < 4; ++dt) {
      const f16* lvr = &lv[bufi * 4096 + (dt * 16 + n) * 64];
#pragma unroll
      for (int st = 0; st < 4; ++st) {
        const f16x4 va = *(const f16x4*)(lvr + vswz[st]);
        acc[0][dt] = MFMA16(va, pq[0][st], acc[0][dt]);
        acc[1][dt] = MFMA16(va, pq[1][st], acc[1][dt]);
      }
    }
    __builtin_amdgcn_s_barrier();         // reads done before buf refill
  }

  float lred[2];
#pragma unroll
  for (int g = 0; g < 2; ++g) {
    float l = ll[g];
    l += __shfl_xor(l, 16);
    l += __shfl_xor(l, 32);
    lred[g] = l;
  }

  if (NSPLIT == 1) {
#pragma unroll
    for (int g = 0; g < 2; ++g) {
      const float inv = 1.0f / lred[g];
      const int q = row0 + g * 16 + n;
#pragma unroll
      for (int t = 0; t < 4; ++t) {
        f32x4 o = acc[g][t];
#pragma unroll
        for (int r = 0; r < 4; ++r) o[r] *= inv;
        *(f32x4*)(outp + (size_t)q * DDIM + t * 16 + quad * 4) = o;
      }
    }
  } else {
#pragma unroll
    for (int g = 0; g < 2; ++g) {
      const int q = row0 + g * 16 + n;
#pragma unroll
      for (int t = 0; t < 4; ++t)
        *(f16x4*)(pacc + ((size_t)split * NROW + q) * DDIM + t * 16 + quad * 4) =
            cvt4(acc[g][t][0], acc[g][t][1], acc[g][t][2], acc[g][t][3]);
      if (quad == 0) {
        pm[split * NROW + q] = m[g];
        pl[split * NROW + q] = lred[g];
      }
    }
  }
}

// ---------------- attn split-K combine (f16 partials) ----------------
template <int NSPLIT>
__global__ __launch_bounds__(256) void combine_kernel(const f16* __restrict__ pacc,
                                                      const float* __restrict__ pm,
                                                      const float* __restrict__ pl,
                                                      float* __restrict__ out) {
  const int idx = blockIdx.x * 256 + threadIdx.x;  // NROW*16 units
  const int row = idx >> 4;
  const int c = (idx & 15) * 4;
  float mm = pm[row];
#pragma unroll
  for (int s = 1; s < NSPLIT; ++s) mm = fmaxf(mm, pm[s * NROW + row]);
  float L = 0.f;
  f32x4 o = (f32x4){0.f, 0.f, 0.f, 0.f};
#pragma unroll
  for (int s = 0; s < NSPLIT; ++s) {
    const float e = __builtin_amdgcn_exp2f(pm[s * NROW + row] - mm);
    L += pl[s * NROW + row] * e;
    const f16x4 a = *(const f16x4*)(pacc + ((size_t)s * NROW + row) * DDIM + c);
#pragma unroll
    for (int j = 0; j < 4; ++j) o[j] += (float)a[j] * e;
  }
  const float inv = 1.0f / L;
#pragma unroll
  for (int j = 0; j < 4; ++j) o[j] *= inv;
  *(f32x4*)(out + (size_t)row * DDIM + c) = o;
}

extern "C" void kernel_launch(void* const* d_in, const int* in_sizes, int n_in,
                              void* d_out, int out_size, void* d_ws, size_t ws_size,
                              hipStream_t stream) {
  const float* x  = (const float*)d_in[0];
  const float* Wq = (const float*)d_in[1];
  const float* bq = (const float*)d_in[2];
  const float* Wk = (const float*)d_in[3];
  const float* bk = (const float*)d_in[4];
  const float* Wv = (const float*)d_in[5];
  const float* bv = (const float*)d_in[6];
  float* out = (float*)d_out;

  f16* wf2 = (f16*)d_ws;                      // 3*64*1024 f16, mt-major slots
  f16* qs = wf2 + 3 * 65536;
  f16* ks = qs + (size_t)SEG;                 // block-swizzled
  f16* vc = ks + (size_t)SEG;                 // chunk-major tiles, swizzled
  f16* pacc = vc + (size_t)SEG;               // [NSPL][NROW][64] f16 attn partials
  float* pm = (float*)(pacc + (size_t)NSPL * SEG);
  float* pl = pm + (size_t)NSPL * NROW;
  const size_t need = (size_t)((char*)(pl + (size_t)NSPL * NROW) - (char*)d_ws);

  prep_w_kernel<<<dim3(96), dim3(256), 0, stream>>>(Wq, Wk, Wv, wf2);
  proj_kernel<<<dim3(NROW / 16), dim3(256), 0, stream>>>(x, wf2, bq, bk, bv, qs, ks, vc);

  if (ws_size >= need) {
    // MEASUREMENT: attn launched 3x (idempotent) -> dur delta = 2x attn dur.
    attn_kernel<NSPL><<<dim3(128 * NSPL), dim3(256), 0, stream>>>(qs, ks, vc, nullptr, pacc, pm, pl);
    attn_kernel<NSPL><<<dim3(128 * NSPL), dim3(256), 0, stream>>>(qs, ks, vc, nullptr, pacc, pm, pl);
    attn_kernel<NSPL><<<dim3(128 * NSPL), dim3(256), 0, stream>>>(qs, ks, vc, nullptr, pacc, pm, pl);
    combine_kernel<NSPL><<<dim3(NROW * 16 / 256), dim3(256), 0, stream>>>(pacc, pm, pl, out);
  } else {
    attn_kernel<1><<<dim3(128), dim3(256), 0, stream>>>(qs, ks, vc, out, nullptr, nullptr, nullptr);
  }
}

// Round 9
// 180.352 us; speedup vs baseline: 1.2034x; 1.2034x over previous
//
#include <hip/hip_runtime.h>

#define BATCH 4
#define SEQ   4096
#define CDIM  1024
#define DDIM  64
#define NROW  (BATCH * SEQ)   // 16384
#define NSPL  8               // attn key-split
#define SEG   (NROW * DDIM)   // 1M elements per q/k/v buffer

typedef _Float16 f16;
typedef _Float16 f16x8 __attribute__((ext_vector_type(8)));
typedef _Float16 f16x4 __attribute__((ext_vector_type(4)));
typedef __fp16   h16x2 __attribute__((ext_vector_type(2)));  // cvt_pkrtz return type
typedef float    f32x4 __attribute__((ext_vector_type(4)));

#define MFMA32(a, b, c) __builtin_amdgcn_mfma_f32_16x16x32_f16((a), (b), (c), 0, 0, 0)
#define MFMA16(a, b, c) __builtin_amdgcn_mfma_f32_16x16x16f16((a), (b), (c), 0, 0, 0)

// async global->LDS DMA, 16 B per lane; LDS dest = wave-uniform base + lane*16
#define GLDS(g, l)                                                            \
  __builtin_amdgcn_global_load_lds((const __attribute__((address_space(1))) void*)(g), \
                                   (__attribute__((address_space(3))) void*)(l), 16, 0, 0)

// scores = (q·k)*8 (the /scale bug); softmax in exp2 domain => fold 8*log2(e) into q
#define QSCALE 11.5415603f

__device__ inline f16x8 cvt8(f32x4 a, f32x4 b) {
  h16x2 p0 = __builtin_amdgcn_cvt_pkrtz(a[0], a[1]);
  h16x2 p1 = __builtin_amdgcn_cvt_pkrtz(a[2], a[3]);
  h16x2 p2 = __builtin_amdgcn_cvt_pkrtz(b[0], b[1]);
  h16x2 p3 = __builtin_amdgcn_cvt_pkrtz(b[2], b[3]);
  f16x8 r;
  r[0] = p0[0]; r[1] = p0[1]; r[2] = p1[0]; r[3] = p1[1];
  r[4] = p2[0]; r[5] = p2[1]; r[6] = p3[0]; r[7] = p3[1];
  return r;
}

__device__ inline f16x4 cvt4(float a, float b, float c, float d) {
  h16x2 lo = __builtin_amdgcn_cvt_pkrtz(a, b);
  h16x2 hi = __builtin_amdgcn_cvt_pkrtz(c, d);
  f16x4 r;
  r[0] = lo[0]; r[1] = lo[1]; r[2] = hi[0]; r[3] = hi[1];
  return r;
}

// ---------------- W prep: fp32 -> f16, mt-major fragment order ---------------
__global__ __launch_bounds__(256) void prep_w_kernel(const float* __restrict__ Wq,
                                                     const float* __restrict__ Wk,
                                                     const float* __restrict__ Wv,
                                                     f16* __restrict__ wf2) {
  const int t = blockIdx.x * 256 + threadIdx.x;  // 96 blocks -> 24576 threads
  const int lane = t & 63;
  const int s = t >> 6;                // 0..383
  const int mt = s >> 5, ck = s & 31;
  const int mat = mt >> 2, tile = mt & 3;
  const int n = lane & 15, quad = lane >> 4;
  const float* W = (mat == 0) ? Wq : (mat == 1) ? Wk : Wv;
  const float* src = W + (size_t)(tile * 16 + n) * CDIM + ck * 32 + quad * 8;
  const f32x4 a = *(const f32x4*)src;
  const f32x4 b = *(const f32x4*)(src + 4);
  *(f16x8*)(wf2 + (size_t)t * 8) = cvt8(a, b);
}

// ---------------- fused QKV projection: DMA-staged x, deep pipeline ----------
// (unchanged from round 7)
__global__ __launch_bounds__(256, 4) void proj_kernel(const float* __restrict__ x,
                                                      const f16* __restrict__ wf2,
                                                      const float* __restrict__ bq,
                                                      const float* __restrict__ bk,
                                                      const float* __restrict__ bv,
                                                      f16* __restrict__ qs,
                                                      f16* __restrict__ ks,
                                                      f16* __restrict__ vc) {
  __shared__ __attribute__((aligned(16))) char lx[3 * 8192];  // 3 bufs x 16rows x 512B swz
  const int tid = threadIdx.x, lane = tid & 63, w = tid >> 6;  // w 0..3
  const int n = lane & 15, quad = lane >> 4;
  const int rowbase = blockIdx.x * 16;
  const int mtb = 3 * w;

  const float* xsrc[2];
#pragma unroll
  for (int j = 0; j < 2; ++j) {
    const int id = 2 * w + j;
    const int r = id * 2 + (lane >> 5);
    const int c = (lane & 31) ^ r;
    xsrc[j] = x + (size_t)(rowbase + r) * CDIM + c * 4;
  }

  auto issue = [&](int ck, int bufi) {
    char* base = &lx[bufi * 8192];
#pragma unroll
    for (int j = 0; j < 2; ++j)
      GLDS(xsrc[j] + ck * 128, base + (2 * w + j) * 1024);
  };

  const f16* wl = wf2 + (size_t)mtb * 16384 + lane * 8;  // + (ck*4+kk)*512

  f32x4 acc[3];
#pragma unroll
  for (int i = 0; i < 3; ++i) acc[i] = (f32x4){0.f, 0.f, 0.f, 0.f};

  issue(0, 0);
  issue(1, 1);
  for (int ck = 0; ck < 8; ++ck) {
    const int bufi = ck % 3;
    if (ck + 2 < 8) issue(ck + 2, (ck + 2) % 3);
    if (ck + 2 < 8)      asm volatile("s_waitcnt vmcnt(4)" ::: "memory");
    else if (ck + 1 < 8) asm volatile("s_waitcnt vmcnt(2)" ::: "memory");
    else                 asm volatile("s_waitcnt vmcnt(0)" ::: "memory");
    __builtin_amdgcn_s_barrier();         // whole tile ck is now in LDS
    __builtin_amdgcn_sched_barrier(0);
    const char* xb = &lx[bufi * 8192] + n * 512;
#pragma unroll
    for (int kk = 0; kk < 4; ++kk) {
      const int c1 = kk * 8 + quad * 2;
      const f32x4 xa = *(const f32x4*)(xb + ((c1 ^ n) << 4));
      const f32x4 xc = *(const f32x4*)(xb + (((c1 + 1) ^ n) << 4));
      const f16x8 af = cvt8(xa, xc);
      const f16* wq = wl + (size_t)(ck * 4 + kk) * 512;
      const f16x8 w0 = *(const f16x8*)(wq);
      const f16x8 w1 = *(const f16x8*)(wq + 16384);
      const f16x8 w2 = *(const f16x8*)(wq + 32768);
      acc[0] = MFMA32(af, w0, acc[0]);
      acc[1] = MFMA32(af, w1, acc[1]);
      acc[2] = MFMA32(af, w2, acc[2]);
    }
    __builtin_amdgcn_s_barrier();         // reads done before buf refill
  }

  // epilogue: bias + final layouts (q*QSCALE, k swizzled, v tiles)
  const int r0 = rowbase + quad * 4;
#pragma unroll
  for (int i2 = 0; i2 < 3; ++i2) {
    const int mt = mtb + i2;
    const int mat = mt >> 2, tile = mt & 3;
    const int d = tile * 16 + n;  // d&15 == n
    const f32x4 aa = acc[i2];
    if (mat == 0) {
      const float bi = bq[d];
#pragma unroll
      for (int r = 0; r < 4; ++r)
        qs[(size_t)(r0 + r) * DDIM + d] = (f16)((aa[r] + bi) * QSCALE);
    } else if (mat == 1) {
      const float bi = bk[d];
#pragma unroll
      for (int r = 0; r < 4; ++r) {
        const int tt = r0 + r;
        const int col = ((((d >> 3) ^ (tt & 7)) << 3) | (d & 7));
        ks[(size_t)tt * DDIM + col] = (f16)(aa[r] + bi);
      }
    } else {
      const float bi = bv[d];
      const int bb = r0 >> 12;
      const int tl = r0 & (SEQ - 1);
      const int ck2 = tl >> 6;
      const int bsw = (((tl & 63) >> 2) ^ n) << 2;
      *(f16x4*)(vc + ((size_t)(bb * 64 + ck2) * 64 + d) * 64 + bsw) =
          cvt4(aa[0] + bi, aa[1] + bi, aa[2] + bi, aa[3] + bi);
    }
  }
}

// ---------------- flash attention: software-pipelined S'-lookahead -----------
// Round-8 measurement: attn = 30 us, ~2x its overlapped pipe floor. Cause:
// phase lockstep -- QK(MFMA+LDS) -> softmax(VALU/trans) -> PV(MFMA+LDS) run
// serially per wave AND barrier-aligned across waves, so pipes idle in turn.
// Restructure (T15-style): compute S'(c+1) during iteration c -- independent
// of softmax(c)/PV(c), K(c+1) already in LDS (issued 2 ahead) -> compiler
// interleaves its 16 MFMA32 + 8 ds_reads into softmax stalls. Issue order
// K,K,V,V so entry vmcnt(2) = {chunk c complete, chunk c+1 K complete};
// issue() moved AFTER the entry barrier -> trailing barrier removed (1
// barrier/chunk). Two named S-buffers ping-ponged by a 2-stepped loop
// (rule #20; NC even). Defer-rescale: skip alpha/rescale when no column's
// max grew (exact -- alpha would be 1).
template <int NSPLIT>
__global__ __launch_bounds__(256, 3) void attn_kernel(const f16* __restrict__ qs,
                                                      const f16* __restrict__ ks,
                                                      const f16* __restrict__ vc,
                                                      float* __restrict__ outp,
                                                      f16* __restrict__ pacc,
                                                      float* __restrict__ pm,
                                                      float* __restrict__ pl) {
  __shared__ __attribute__((aligned(16))) f16 lk[3 * 4096];  // [buf][key][64 d swz]
  __shared__ __attribute__((aligned(16))) f16 lv[3 * 4096];  // [buf][d][64 key swz]
  const int tid = threadIdx.x, lane = tid & 63, w = tid >> 6;
  const int n = lane & 15, quad = lane >> 4;
  const int split = blockIdx.x % NSPLIT;
  const int rowblk = blockIdx.x / NSPLIT;
  const int row0 = rowblk * 128 + w * 32;
  const int bb = row0 >> 12;
  const int kbase = split * (SEQ / NSPLIT);
  const int kc0 = kbase >> 6;
  const int NC = SEQ / NSPLIT / 64;   // 8 (or 64 for NSPLIT=1) -- even

  const f16* ksb = ks + (size_t)bb * SEQ * DDIM;
  const f16* vcb = vc + (size_t)bb * 64 * 4096;

  // issue order K,K,V,V (vmcnt(2) at entry => this chunk all + next chunk K)
  auto issue = [&](int c, int bufi) {
#pragma unroll
    for (int i = 0; i < 2; ++i) {
      const int id = 2 * w + i;
      GLDS(ksb + (size_t)(kbase + c * 64) * 64 + id * 512 + lane * 8,
           &lk[bufi * 4096 + id * 512]);
    }
#pragma unroll
    for (int i = 0; i < 2; ++i) {
      const int id = 2 * w + i;
      GLDS(vcb + (size_t)(kc0 + c) * 4096 + id * 512 + lane * 8,
           &lv[bufi * 4096 + id * 512]);
    }
  };

  // persistent Q B-fragments (16x16x32): B[k=d=quad*8+j][col=q=n]
  f16x8 qf[2][2];
#pragma unroll
  for (int g = 0; g < 2; ++g)
#pragma unroll
    for (int hh = 0; hh < 2; ++hh)
      qf[g][hh] = *(const f16x8*)(qs + (size_t)(row0 + g * 16 + n) * DDIM + hh * 32 + quad * 8);

  // swizzle read offsets (per-lane constants)
  const int kswz = (quad ^ (n & 7)) << 3;          // klo block; khi = kswz ^ 32
  int vswz[4];
#pragma unroll
  for (int st = 0; st < 4; ++st) vswz[st] = ((((st << 2) | quad) ^ n) << 2);

  f32x4 acc[2][4];
  float m[2] = {-1e30f, -1e30f}, ll[2] = {0.f, 0.f};
#pragma unroll
  for (int g = 0; g < 2; ++g)
#pragma unroll
    for (int t = 0; t < 4; ++t) acc[g][t] = (f32x4){0.f, 0.f, 0.f, 0.f};

  // S' = K·Q^T for one chunk into sO
  auto qk = [&](int bufi, f32x4 (&sO)[2][4]) {
#pragma unroll
    for (int st = 0; st < 4; ++st) {
      const f16* lkr = &lk[bufi * 4096 + (st * 16 + n) * 64];
      const f16x8 klo = *(const f16x8*)(lkr + kswz);
      const f16x8 khi = *(const f16x8*)(lkr + (kswz ^ 32));
#pragma unroll
      for (int g = 0; g < 2; ++g) {
        f32x4 z = (f32x4){0.f, 0.f, 0.f, 0.f};
        z = MFMA32(klo, qf[g][0], z);
        sO[g][st] = MFMA32(khi, qf[g][1], z);
      }
    }
  };

  // one pipeline step: softmax+PV on scur (chunk c); S'(c+1) into snxt
  auto step = [&](int c, f32x4 (&scur)[2][4], f32x4 (&snxt)[2][4]) {
    if (c > 0) {
      __builtin_amdgcn_sched_barrier(0);
      if (c + 1 < NC) asm volatile("s_waitcnt vmcnt(2)" ::: "memory");
      else            asm volatile("s_waitcnt vmcnt(0)" ::: "memory");
      __builtin_amdgcn_s_barrier();       // chunk c V + chunk c+1 K visible;
      __builtin_amdgcn_sched_barrier(0);  // all waves done with buf (c-1)%3
    }
    if (c + 2 < NC) issue(c + 2, (c + 2) % 3);  // overwrites buf (c-1)%3: safe
    if (c + 1 < NC) qk((c + 1) % 3, snxt);      // independent of softmax below

    // per-lane online softmax on scur; P packed as 16x16x16 B-fragments
    f16x4 pq[2][4];
#pragma unroll
    for (int g = 0; g < 2; ++g) {
      f32x4 mx;
#pragma unroll
      for (int r = 0; r < 4; ++r)
        mx[r] = fmaxf(fmaxf(scur[g][0][r], scur[g][1][r]),
                      fmaxf(scur[g][2][r], scur[g][3][r]));
      float mloc = fmaxf(fmaxf(mx[0], mx[1]), fmaxf(mx[2], mx[3]));
      mloc = fmaxf(mloc, __shfl_xor(mloc, 16));
      mloc = fmaxf(mloc, __shfl_xor(mloc, 32));
      if (__any(mloc > m[g])) {           // wave-uniform; exact skip otherwise
        const float mnew = fmaxf(m[g], mloc);
        const float alpha = __builtin_amdgcn_exp2f(m[g] - mnew);
        m[g] = mnew;
        ll[g] *= alpha;
#pragma unroll
        for (int t = 0; t < 4; ++t) acc[g][t] *= alpha;
      }
      float psum = 0.f;
#pragma unroll
      for (int st = 0; st < 4; ++st) {
        f32x4 p;
#pragma unroll
        for (int r = 0; r < 4; ++r) p[r] = __builtin_amdgcn_exp2f(scur[g][st][r] - m[g]);
        psum += (p[0] + p[1]) + (p[2] + p[3]);
        pq[g][st] = cvt4(p[0], p[1], p[2], p[3]);
      }
      ll[g] += psum;
    }

    // O^T += V^T·P^T : A = V^T frag [m=d][k=key quad*4+j] (swizzled LDS read)
    const int bufi = c % 3;
#pragma unroll
    for (int dt = 0; dt < 4; ++dt) {
      const f16* lvr = &lv[bufi * 4096 + (dt * 16 + n) * 64];
#pragma unroll
      for (int st = 0; st < 4; ++st) {
        const f16x4 va = *(const f16x4*)(lvr + vswz[st]);
        acc[0][dt] = MFMA16(va, pq[0][st], acc[0][dt]);
        acc[1][dt] = MFMA16(va, pq[1][st], acc[1][dt]);
      }
    }
  };

  // prologue: 2 chunks in flight; wait chunk0 full + chunk1 K; S'(0)
  issue(0, 0);
  issue(1, 1);
  asm volatile("s_waitcnt vmcnt(2)" ::: "memory");
  __builtin_amdgcn_s_barrier();
  __builtin_amdgcn_sched_barrier(0);
  f32x4 sA[2][4], sB[2][4];
  qk(0, sA);
  for (int c = 0; c < NC; c += 2) {   // NC even; named ping-pong (rule #20)
    step(c, sA, sB);
    step(c + 1, sB, sA);
  }

  float lred[2];
#pragma unroll
  for (int g = 0; g < 2; ++g) {
    float l = ll[g];
    l += __shfl_xor(l, 16);
    l += __shfl_xor(l, 32);
    lred[g] = l;
  }

  if (NSPLIT == 1) {
#pragma unroll
    for (int g = 0; g < 2; ++g) {
      const float inv = 1.0f / lred[g];
      const int q = row0 + g * 16 + n;
#pragma unroll
      for (int t = 0; t < 4; ++t) {
        f32x4 o = acc[g][t];
#pragma unroll
        for (int r = 0; r < 4; ++r) o[r] *= inv;
        *(f32x4*)(outp + (size_t)q * DDIM + t * 16 + quad * 4) = o;
      }
    }
  } else {
#pragma unroll
    for (int g = 0; g < 2; ++g) {
      const int q = row0 + g * 16 + n;
#pragma unroll
      for (int t = 0; t < 4; ++t)
        *(f16x4*)(pacc + ((size_t)split * NROW + q) * DDIM + t * 16 + quad * 4) =
            cvt4(acc[g][t][0], acc[g][t][1], acc[g][t][2], acc[g][t][3]);
      if (quad == 0) {
        pm[split * NROW + q] = m[g];
        pl[split * NROW + q] = lred[g];
      }
    }
  }
}

// ---------------- attn split-K combine (f16 partials) ----------------
template <int NSPLIT>
__global__ __launch_bounds__(256) void combine_kernel(const f16* __restrict__ pacc,
                                                      const float* __restrict__ pm,
                                                      const float* __restrict__ pl,
                                                      float* __restrict__ out) {
  const int idx = blockIdx.x * 256 + threadIdx.x;  // NROW*16 units
  const int row = idx >> 4;
  const int c = (idx & 15) * 4;
  float mm = pm[row];
#pragma unroll
  for (int s = 1; s < NSPLIT; ++s) mm = fmaxf(mm, pm[s * NROW + row]);
  float L = 0.f;
  f32x4 o = (f32x4){0.f, 0.f, 0.f, 0.f};
#pragma unroll
  for (int s = 0; s < NSPLIT; ++s) {
    const float e = __builtin_amdgcn_exp2f(pm[s * NROW + row] - mm);
    L += pl[s * NROW + row] * e;
    const f16x4 a = *(const f16x4*)(pacc + ((size_t)s * NROW + row) * DDIM + c);
#pragma unroll
    for (int j = 0; j < 4; ++j) o[j] += (float)a[j] * e;
  }
  const float inv = 1.0f / L;
#pragma unroll
  for (int j = 0; j < 4; ++j) o[j] *= inv;
  *(f32x4*)(out + (size_t)row * DDIM + c) = o;
}

extern "C" void kernel_launch(void* const* d_in, const int* in_sizes, int n_in,
                              void* d_out, int out_size, void* d_ws, size_t ws_size,
                              hipStream_t stream) {
  const float* x  = (const float*)d_in[0];
  const float* Wq = (const float*)d_in[1];
  const float* bq = (const float*)d_in[2];
  const float* Wk = (const float*)d_in[3];
  const float* bk = (const float*)d_in[4];
  const float* Wv = (const float*)d_in[5];
  const float* bv = (const float*)d_in[6];
  float* out = (float*)d_out;

  f16* wf2 = (f16*)d_ws;                      // 3*64*1024 f16, mt-major slots
  f16* qs = wf2 + 3 * 65536;
  f16* ks = qs + (size_t)SEG;                 // block-swizzled
  f16* vc = ks + (size_t)SEG;                 // chunk-major tiles, swizzled
  f16* pacc = vc + (size_t)SEG;               // [NSPL][NROW][64] f16 attn partials
  float* pm = (float*)(pacc + (size_t)NSPL * SEG);
  float* pl = pm + (size_t)NSPL * NROW;
  const size_t need = (size_t)((char*)(pl + (size_t)NSPL * NROW) - (char*)d_ws);

  prep_w_kernel<<<dim3(96), dim3(256), 0, stream>>>(Wq, Wk, Wv, wf2);
  proj_kernel<<<dim3(NROW / 16), dim3(256), 0, stream>>>(x, wf2, bq, bk, bv, qs, ks, vc);

  if (ws_size >= need) {
    attn_kernel<NSPL><<<dim3(128 * NSPL), dim3(256), 0, stream>>>(qs, ks, vc, nullptr, pacc, pm, pl);
    combine_kernel<NSPL><<<dim3(NROW * 16 / 256), dim3(256), 0, stream>>>(pacc, pm, pl, out);
  } else {
    attn_kernel<1><<<dim3(128), dim3(256), 0, stream>>>(qs, ks, vc, out, nullptr, nullptr, nullptr);
  }
}

// Round 10
// 156.791 us; speedup vs baseline: 1.3843x; 1.1503x over previous
//
#include <hip/hip_runtime.h>

#define BATCH 4
#define SEQ   4096
#define CDIM  1024
#define DDIM  64
#define NROW  (BATCH * SEQ)   // 16384
#define NSPL  8               // attn key-split
#define SEG   (NROW * DDIM)   // 1M elements per q/k/v buffer

typedef _Float16 f16;
typedef _Float16 f16x8 __attribute__((ext_vector_type(8)));
typedef _Float16 f16x4 __attribute__((ext_vector_type(4)));
typedef __fp16   h16x2 __attribute__((ext_vector_type(2)));  // cvt_pkrtz return type
typedef float    f32x4 __attribute__((ext_vector_type(4)));

#define MFMA32(a, b, c) __builtin_amdgcn_mfma_f32_16x16x32_f16((a), (b), (c), 0, 0, 0)
#define MFMA16(a, b, c) __builtin_amdgcn_mfma_f32_16x16x16f16((a), (b), (c), 0, 0, 0)

// async global->LDS DMA, 16 B per lane; LDS dest = wave-uniform base + lane*16
#define GLDS(g, l)                                                            \
  __builtin_amdgcn_global_load_lds((const __attribute__((address_space(1))) void*)(g), \
                                   (__attribute__((address_space(3))) void*)(l), 16, 0, 0)

// scores = (q·k)*8 (the /scale bug); softmax in exp2 domain => fold 8*log2(e) into q
#define QSCALE 11.5415603f

__device__ inline f16x8 cvt8(f32x4 a, f32x4 b) {
  h16x2 p0 = __builtin_amdgcn_cvt_pkrtz(a[0], a[1]);
  h16x2 p1 = __builtin_amdgcn_cvt_pkrtz(a[2], a[3]);
  h16x2 p2 = __builtin_amdgcn_cvt_pkrtz(b[0], b[1]);
  h16x2 p3 = __builtin_amdgcn_cvt_pkrtz(b[2], b[3]);
  f16x8 r;
  r[0] = p0[0]; r[1] = p0[1]; r[2] = p1[0]; r[3] = p1[1];
  r[4] = p2[0]; r[5] = p2[1]; r[6] = p3[0]; r[7] = p3[1];
  return r;
}

__device__ inline f16x4 cvt4(float a, float b, float c, float d) {
  h16x2 lo = __builtin_amdgcn_cvt_pkrtz(a, b);
  h16x2 hi = __builtin_amdgcn_cvt_pkrtz(c, d);
  f16x4 r;
  r[0] = lo[0]; r[1] = lo[1]; r[2] = hi[0]; r[3] = hi[1];
  return r;
}

// ---------------- W prep: fp32 -> f16, mt-major fragment order ---------------
__global__ __launch_bounds__(256) void prep_w_kernel(const float* __restrict__ Wq,
                                                     const float* __restrict__ Wk,
                                                     const float* __restrict__ Wv,
                                                     f16* __restrict__ wf2) {
  const int t = blockIdx.x * 256 + threadIdx.x;  // 96 blocks -> 24576 threads
  const int lane = t & 63;
  const int s = t >> 6;                // 0..383
  const int mt = s >> 5, ck = s & 31;
  const int mat = mt >> 2, tile = mt & 3;
  const int n = lane & 15, quad = lane >> 4;
  const float* W = (mat == 0) ? Wq : (mat == 1) ? Wk : Wv;
  const float* src = W + (size_t)(tile * 16 + n) * CDIM + ck * 32 + quad * 8;
  const f32x4 a = *(const f32x4*)src;
  const f32x4 b = *(const f32x4*)(src + 4);
  *(f16x8*)(wf2 + (size_t)t * 8) = cvt8(a, b);
}

// ---------------- fused QKV projection: DMA-staged x, deep pipeline ----------
// (unchanged from round 7)
__global__ __launch_bounds__(256, 4) void proj_kernel(const float* __restrict__ x,
                                                      const f16* __restrict__ wf2,
                                                      const float* __restrict__ bq,
                                                      const float* __restrict__ bk,
                                                      const float* __restrict__ bv,
                                                      f16* __restrict__ qs,
                                                      f16* __restrict__ ks,
                                                      f16* __restrict__ vc) {
  __shared__ __attribute__((aligned(16))) char lx[3 * 8192];  // 3 bufs x 16rows x 512B swz
  const int tid = threadIdx.x, lane = tid & 63, w = tid >> 6;  // w 0..3
  const int n = lane & 15, quad = lane >> 4;
  const int rowbase = blockIdx.x * 16;
  const int mtb = 3 * w;

  const float* xsrc[2];
#pragma unroll
  for (int j = 0; j < 2; ++j) {
    const int id = 2 * w + j;
    const int r = id * 2 + (lane >> 5);
    const int c = (lane & 31) ^ r;
    xsrc[j] = x + (size_t)(rowbase + r) * CDIM + c * 4;
  }

  auto issue = [&](int ck, int bufi) {
    char* base = &lx[bufi * 8192];
#pragma unroll
    for (int j = 0; j < 2; ++j)
      GLDS(xsrc[j] + ck * 128, base + (2 * w + j) * 1024);
  };

  const f16* wl = wf2 + (size_t)mtb * 16384 + lane * 8;  // + (ck*4+kk)*512

  f32x4 acc[3];
#pragma unroll
  for (int i = 0; i < 3; ++i) acc[i] = (f32x4){0.f, 0.f, 0.f, 0.f};

  issue(0, 0);
  issue(1, 1);
  for (int ck = 0; ck < 8; ++ck) {
    const int bufi = ck % 3;
    if (ck + 2 < 8) issue(ck + 2, (ck + 2) % 3);
    if (ck + 2 < 8)      asm volatile("s_waitcnt vmcnt(4)" ::: "memory");
    else if (ck + 1 < 8) asm volatile("s_waitcnt vmcnt(2)" ::: "memory");
    else                 asm volatile("s_waitcnt vmcnt(0)" ::: "memory");
    __builtin_amdgcn_s_barrier();         // whole tile ck is now in LDS
    __builtin_amdgcn_sched_barrier(0);
    const char* xb = &lx[bufi * 8192] + n * 512;
#pragma unroll
    for (int kk = 0; kk < 4; ++kk) {
      const int c1 = kk * 8 + quad * 2;
      const f32x4 xa = *(const f32x4*)(xb + ((c1 ^ n) << 4));
      const f32x4 xc = *(const f32x4*)(xb + (((c1 + 1) ^ n) << 4));
      const f16x8 af = cvt8(xa, xc);
      const f16* wq = wl + (size_t)(ck * 4 + kk) * 512;
      const f16x8 w0 = *(const f16x8*)(wq);
      const f16x8 w1 = *(const f16x8*)(wq + 16384);
      const f16x8 w2 = *(const f16x8*)(wq + 32768);
      acc[0] = MFMA32(af, w0, acc[0]);
      acc[1] = MFMA32(af, w1, acc[1]);
      acc[2] = MFMA32(af, w2, acc[2]);
    }
    __builtin_amdgcn_s_barrier();         // reads done before buf refill
  }

  // epilogue: bias + final layouts (q*QSCALE, k swizzled, v tiles)
  const int r0 = rowbase + quad * 4;
#pragma unroll
  for (int i2 = 0; i2 < 3; ++i2) {
    const int mt = mtb + i2;
    const int mat = mt >> 2, tile = mt & 3;
    const int d = tile * 16 + n;  // d&15 == n
    const f32x4 aa = acc[i2];
    if (mat == 0) {
      const float bi = bq[d];
#pragma unroll
      for (int r = 0; r < 4; ++r)
        qs[(size_t)(r0 + r) * DDIM + d] = (f16)((aa[r] + bi) * QSCALE);
    } else if (mat == 1) {
      const float bi = bk[d];
#pragma unroll
      for (int r = 0; r < 4; ++r) {
        const int tt = r0 + r;
        const int col = ((((d >> 3) ^ (tt & 7)) << 3) | (d & 7));
        ks[(size_t)tt * DDIM + col] = (f16)(aa[r] + bi);
      }
    } else {
      const float bi = bv[d];
      const int bb = r0 >> 12;
      const int tl = r0 & (SEQ - 1);
      const int ck2 = tl >> 6;
      const int bsw = (((tl & 63) >> 2) ^ n) << 2;
      *(f16x4*)(vc + ((size_t)(bb * 64 + ck2) * 64 + d) * 64 + bsw) =
          cvt4(aa[0] + bi, aa[1] + bi, aa[2] + bi, aa[3] + bi);
    }
  }
}

// ---------------- flash attention: round-7 skeleton, 64 rows/wave (G=4) ------
// Round-9 post-mortem: S'-lookahead REGRESSED 30->58 us; profile (first direct
// one) shows latency-bound: MfmaUtil 16 / VALU 25 / occ 21, nothing saturated.
// Per-CU busy work is only ~4-8 us -> the per-chunk serial chain (vmcnt ->
// barrier -> MFMA chain -> softmax -> PV -> barrier) dominates and barrier-
// lockstepped waves all sit in the same chain. Fix: amortize the chain --
// KEEP the verified round-7 skeleton exactly (3 bufs, counted vmcnt, 2
// barriers/chunk, always-rescale softmax => bit-identical output) but each
// wave owns 64 Q-rows (4 groups): K/V frags reused 4x, 4 independent softmax
// chains of ILP per chunk, fixed per-chunk costs paid half as often. Grid
// 512 = exactly 2 blocks/CU (zero tail); duplicate K/V staging halves.
template <int NSPLIT>
__global__ __launch_bounds__(256, 2) void attn_kernel(const f16* __restrict__ qs,
                                                      const f16* __restrict__ ks,
                                                      const f16* __restrict__ vc,
                                                      float* __restrict__ outp,
                                                      f16* __restrict__ pacc,
                                                      float* __restrict__ pm,
                                                      float* __restrict__ pl) {
  __shared__ __attribute__((aligned(16))) f16 lk[3 * 4096];  // [buf][key][64 d swz]
  __shared__ __attribute__((aligned(16))) f16 lv[3 * 4096];  // [buf][d][64 key swz]
  const int tid = threadIdx.x, lane = tid & 63, w = tid >> 6;
  const int n = lane & 15, quad = lane >> 4;
  const int split = blockIdx.x % NSPLIT;
  const int rowblk = blockIdx.x / NSPLIT;
  const int row0 = rowblk * 256 + w * 64;   // wave owns 64 rows (4 groups)
  const int bb = row0 >> 12;
  const int kbase = split * (SEQ / NSPLIT);
  const int kc0 = kbase >> 6;
  const int NC = SEQ / NSPLIT / 64;

  const f16* ksb = ks + (size_t)bb * SEQ * DDIM;
  const f16* vcb = vc + (size_t)bb * 64 * 4096;

  auto issue = [&](int c, int bufi) {
#pragma unroll
    for (int i = 0; i < 2; ++i) {
      const int id = 2 * w + i;
      GLDS(ksb + (size_t)(kbase + c * 64) * 64 + id * 512 + lane * 8,
           &lk[bufi * 4096 + id * 512]);
      GLDS(vcb + (size_t)(kc0 + c) * 4096 + id * 512 + lane * 8,
           &lv[bufi * 4096 + id * 512]);
    }
  };

  // persistent Q B-fragments (16x16x32): B[k=d=quad*8+j][col=q=n]
  f16x8 qf[4][2];
#pragma unroll
  for (int g = 0; g < 4; ++g)
#pragma unroll
    for (int hh = 0; hh < 2; ++hh)
      qf[g][hh] = *(const f16x8*)(qs + (size_t)(row0 + g * 16 + n) * DDIM + hh * 32 + quad * 8);

  // swizzle read offsets (per-lane constants)
  const int kswz = (quad ^ (n & 7)) << 3;          // klo block; khi = kswz ^ 32
  int vswz[4];
#pragma unroll
  for (int st = 0; st < 4; ++st) vswz[st] = ((((st << 2) | quad) ^ n) << 2);

  f32x4 acc[4][4];
  float m[4] = {-1e30f, -1e30f, -1e30f, -1e30f}, ll[4] = {0.f, 0.f, 0.f, 0.f};
#pragma unroll
  for (int g = 0; g < 4; ++g)
#pragma unroll
    for (int t = 0; t < 4; ++t) acc[g][t] = (f32x4){0.f, 0.f, 0.f, 0.f};

  issue(0, 0);
  issue(1, 1);
  for (int c = 0; c < NC; ++c) {
    const int bufi = c % 3;
    if (c + 2 < NC) issue(c + 2, (c + 2) % 3);
    // wait for THIS chunk's 4 GLDS only; newer chunks stay in flight
    if (c + 2 < NC)      asm volatile("s_waitcnt vmcnt(8)" ::: "memory");
    else if (c + 1 < NC) asm volatile("s_waitcnt vmcnt(4)" ::: "memory");
    else                 asm volatile("s_waitcnt vmcnt(0)" ::: "memory");
    __builtin_amdgcn_s_barrier();         // whole K/V tile c is now in LDS
    __builtin_amdgcn_sched_barrier(0);

    // S' = K·Q^T : K frags reused across 4 groups
    f32x4 s[4][4];
#pragma unroll
    for (int st = 0; st < 4; ++st) {
      const f16* lkr = &lk[bufi * 4096 + (st * 16 + n) * 64];
      const f16x8 klo = *(const f16x8*)(lkr + kswz);
      const f16x8 khi = *(const f16x8*)(lkr + (kswz ^ 32));
#pragma unroll
      for (int g = 0; g < 4; ++g) {
        f32x4 z = (f32x4){0.f, 0.f, 0.f, 0.f};
        z = MFMA32(klo, qf[g][0], z);
        s[g][st] = MFMA32(khi, qf[g][1], z);
      }
    }

    // per-lane online softmax; P packed directly as 16x16x16 B-fragments
    f16x4 pq[4][4];
#pragma unroll
    for (int g = 0; g < 4; ++g) {
      f32x4 mx;
#pragma unroll
      for (int r = 0; r < 4; ++r)
        mx[r] = fmaxf(fmaxf(s[g][0][r], s[g][1][r]), fmaxf(s[g][2][r], s[g][3][r]));
      float mloc = fmaxf(fmaxf(mx[0], mx[1]), fmaxf(mx[2], mx[3]));
      mloc = fmaxf(mloc, __shfl_xor(mloc, 16));
      mloc = fmaxf(mloc, __shfl_xor(mloc, 32));
      const float mnew = fmaxf(m[g], mloc);
      const float alpha = __builtin_amdgcn_exp2f(m[g] - mnew);
      m[g] = mnew;
      float psum = 0.f;
#pragma unroll
      for (int st = 0; st < 4; ++st) {
        f32x4 p;
#pragma unroll
        for (int r = 0; r < 4; ++r) p[r] = __builtin_amdgcn_exp2f(s[g][st][r] - mnew);
        psum += (p[0] + p[1]) + (p[2] + p[3]);
        pq[g][st] = cvt4(p[0], p[1], p[2], p[3]);
      }
      ll[g] = ll[g] * alpha + psum;
#pragma unroll
      for (int t = 0; t < 4; ++t) acc[g][t] *= alpha;
    }

    // O^T += V^T·P^T : V frags reused across 4 groups
#pragma unroll
    for (int dt = 0; dt < 4; ++dt) {
      const f16* lvr = &lv[bufi * 4096 + (dt * 16 + n) * 64];
#pragma unroll
      for (int st = 0; st < 4; ++st) {
        const f16x4 va = *(const f16x4*)(lvr + vswz[st]);
#pragma unroll
        for (int g = 0; g < 4; ++g)
          acc[g][dt] = MFMA16(va, pq[g][st], acc[g][dt]);
      }
    }
    __builtin_amdgcn_s_barrier();         // reads done before buf refill
  }

  float lred[4];
#pragma unroll
  for (int g = 0; g < 4; ++g) {
    float l = ll[g];
    l += __shfl_xor(l, 16);
    l += __shfl_xor(l, 32);
    lred[g] = l;
  }

  if (NSPLIT == 1) {
#pragma unroll
    for (int g = 0; g < 4; ++g) {
      const float inv = 1.0f / lred[g];
      const int q = row0 + g * 16 + n;
#pragma unroll
      for (int t = 0; t < 4; ++t) {
        f32x4 o = acc[g][t];
#pragma unroll
        for (int r = 0; r < 4; ++r) o[r] *= inv;
        *(f32x4*)(outp + (size_t)q * DDIM + t * 16 + quad * 4) = o;
      }
    }
  } else {
#pragma unroll
    for (int g = 0; g < 4; ++g) {
      const int q = row0 + g * 16 + n;
#pragma unroll
      for (int t = 0; t < 4; ++t)
        *(f16x4*)(pacc + ((size_t)split * NROW + q) * DDIM + t * 16 + quad * 4) =
            cvt4(acc[g][t][0], acc[g][t][1], acc[g][t][2], acc[g][t][3]);
      if (quad == 0) {
        pm[split * NROW + q] = m[g];
        pl[split * NROW + q] = lred[g];
      }
    }
  }
}

// ---------------- attn split-K combine (f16 partials) ----------------
template <int NSPLIT>
__global__ __launch_bounds__(256) void combine_kernel(const f16* __restrict__ pacc,
                                                      const float* __restrict__ pm,
                                                      const float* __restrict__ pl,
                                                      float* __restrict__ out) {
  const int idx = blockIdx.x * 256 + threadIdx.x;  // NROW*16 units
  const int row = idx >> 4;
  const int c = (idx & 15) * 4;
  float mm = pm[row];
#pragma unroll
  for (int s = 1; s < NSPLIT; ++s) mm = fmaxf(mm, pm[s * NROW + row]);
  float L = 0.f;
  f32x4 o = (f32x4){0.f, 0.f, 0.f, 0.f};
#pragma unroll
  for (int s = 0; s < NSPLIT; ++s) {
    const float e = __builtin_amdgcn_exp2f(pm[s * NROW + row] - mm);
    L += pl[s * NROW + row] * e;
    const f16x4 a = *(const f16x4*)(pacc + ((size_t)s * NROW + row) * DDIM + c);
#pragma unroll
    for (int j = 0; j < 4; ++j) o[j] += (float)a[j] * e;
  }
  const float inv = 1.0f / L;
#pragma unroll
  for (int j = 0; j < 4; ++j) o[j] *= inv;
  *(f32x4*)(out + (size_t)row * DDIM + c) = o;
}

extern "C" void kernel_launch(void* const* d_in, const int* in_sizes, int n_in,
                              void* d_out, int out_size, void* d_ws, size_t ws_size,
                              hipStream_t stream) {
  const float* x  = (const float*)d_in[0];
  const float* Wq = (const float*)d_in[1];
  const float* bq = (const float*)d_in[2];
  const float* Wk = (const float*)d_in[3];
  const float* bk = (const float*)d_in[4];
  const float* Wv = (const float*)d_in[5];
  const float* bv = (const float*)d_in[6];
  float* out = (float*)d_out;

  f16* wf2 = (f16*)d_ws;                      // 3*64*1024 f16, mt-major slots
  f16* qs = wf2 + 3 * 65536;
  f16* ks = qs + (size_t)SEG;                 // block-swizzled
  f16* vc = ks + (size_t)SEG;                 // chunk-major tiles, swizzled
  f16* pacc = vc + (size_t)SEG;               // [NSPL][NROW][64] f16 attn partials
  float* pm = (float*)(pacc + (size_t)NSPL * SEG);
  float* pl = pm + (size_t)NSPL * NROW;
  const size_t need = (size_t)((char*)(pl + (size_t)NSPL * NROW) - (char*)d_ws);

  prep_w_kernel<<<dim3(96), dim3(256), 0, stream>>>(Wq, Wk, Wv, wf2);
  proj_kernel<<<dim3(NROW / 16), dim3(256), 0, stream>>>(x, wf2, bq, bk, bv, qs, ks, vc);

  if (ws_size >= need) {
    attn_kernel<NSPL><<<dim3((NROW / 256) * NSPL), dim3(256), 0, stream>>>(qs, ks, vc, nullptr, pacc, pm, pl);
    combine_kernel<NSPL><<<dim3(NROW * 16 / 256), dim3(256), 0, stream>>>(pacc, pm, pl, out);
  } else {
    attn_kernel<1><<<dim3(NROW / 256), dim3(256), 0, stream>>>(qs, ks, vc, out, nullptr, nullptr, nullptr);
  }
}

// Round 11
// 152.229 us; speedup vs baseline: 1.4257x; 1.0300x over previous
//
#include <hip/hip_runtime.h>

#define BATCH 4
#define SEQ   4096
#define CDIM  1024
#define DDIM  64
#define NROW  (BATCH * SEQ)   // 16384
#define NSPL  8               // attn key-split
#define SEG   (NROW * DDIM)   // 1M elements per q/k/v buffer

typedef _Float16 f16;
typedef _Float16 f16x8 __attribute__((ext_vector_type(8)));
typedef _Float16 f16x4 __attribute__((ext_vector_type(4)));
typedef __fp16   h16x2 __attribute__((ext_vector_type(2)));  // cvt_pkrtz return type
typedef float    f32x4 __attribute__((ext_vector_type(4)));

#define MFMA32(a, b, c) __builtin_amdgcn_mfma_f32_16x16x32_f16((a), (b), (c), 0, 0, 0)
#define MFMA16(a, b, c) __builtin_amdgcn_mfma_f32_16x16x16f16((a), (b), (c), 0, 0, 0)

// async global->LDS DMA, 16 B per lane; LDS dest = wave-uniform base + lane*16
#define GLDS(g, l)                                                            \
  __builtin_amdgcn_global_load_lds((const __attribute__((address_space(1))) void*)(g), \
                                   (__attribute__((address_space(3))) void*)(l), 16, 0, 0)

// scores = (q·k)*8 (the /scale bug); softmax in exp2 domain => fold 8*log2(e) into q
#define QSCALE 11.5415603f

__device__ inline f16x8 cvt8(f32x4 a, f32x4 b) {
  h16x2 p0 = __builtin_amdgcn_cvt_pkrtz(a[0], a[1]);
  h16x2 p1 = __builtin_amdgcn_cvt_pkrtz(a[2], a[3]);
  h16x2 p2 = __builtin_amdgcn_cvt_pkrtz(b[0], b[1]);
  h16x2 p3 = __builtin_amdgcn_cvt_pkrtz(b[2], b[3]);
  f16x8 r;
  r[0] = p0[0]; r[1] = p0[1]; r[2] = p1[0]; r[3] = p1[1];
  r[4] = p2[0]; r[5] = p2[1]; r[6] = p3[0]; r[7] = p3[1];
  return r;
}

__device__ inline f16x4 cvt4(float a, float b, float c, float d) {
  h16x2 lo = __builtin_amdgcn_cvt_pkrtz(a, b);
  h16x2 hi = __builtin_amdgcn_cvt_pkrtz(c, d);
  f16x4 r;
  r[0] = lo[0]; r[1] = lo[1]; r[2] = hi[0]; r[3] = hi[1];
  return r;
}

// ---------------- W prep: fp32 -> f16, mt-major fragment order ---------------
__global__ __launch_bounds__(256) void prep_w_kernel(const float* __restrict__ Wq,
                                                     const float* __restrict__ Wk,
                                                     const float* __restrict__ Wv,
                                                     f16* __restrict__ wf2) {
  const int t = blockIdx.x * 256 + threadIdx.x;  // 96 blocks -> 24576 threads
  const int lane = t & 63;
  const int s = t >> 6;                // 0..383
  const int mt = s >> 5, ck = s & 31;
  const int mat = mt >> 2, tile = mt & 3;
  const int n = lane & 15, quad = lane >> 4;
  const float* W = (mat == 0) ? Wq : (mat == 1) ? Wk : Wv;
  const float* src = W + (size_t)(tile * 16 + n) * CDIM + ck * 32 + quad * 8;
  const f32x4 a = *(const f32x4*)src;
  const f32x4 b = *(const f32x4*)(src + 4);
  *(f16x8*)(wf2 + (size_t)t * 8) = cvt8(a, b);
}

// ---------------- fused QKV projection: DMA-staged x, deep pipeline ----------
// (unchanged from round 7)
__global__ __launch_bounds__(256, 4) void proj_kernel(const float* __restrict__ x,
                                                      const f16* __restrict__ wf2,
                                                      const float* __restrict__ bq,
                                                      const float* __restrict__ bk,
                                                      const float* __restrict__ bv,
                                                      f16* __restrict__ qs,
                                                      f16* __restrict__ ks,
                                                      f16* __restrict__ vc) {
  __shared__ __attribute__((aligned(16))) char lx[3 * 8192];  // 3 bufs x 16rows x 512B swz
  const int tid = threadIdx.x, lane = tid & 63, w = tid >> 6;  // w 0..3
  const int n = lane & 15, quad = lane >> 4;
  const int rowbase = blockIdx.x * 16;
  const int mtb = 3 * w;

  const float* xsrc[2];
#pragma unroll
  for (int j = 0; j < 2; ++j) {
    const int id = 2 * w + j;
    const int r = id * 2 + (lane >> 5);
    const int c = (lane & 31) ^ r;
    xsrc[j] = x + (size_t)(rowbase + r) * CDIM + c * 4;
  }

  auto issue = [&](int ck, int bufi) {
    char* base = &lx[bufi * 8192];
#pragma unroll
    for (int j = 0; j < 2; ++j)
      GLDS(xsrc[j] + ck * 128, base + (2 * w + j) * 1024);
  };

  const f16* wl = wf2 + (size_t)mtb * 16384 + lane * 8;  // + (ck*4+kk)*512

  f32x4 acc[3];
#pragma unroll
  for (int i = 0; i < 3; ++i) acc[i] = (f32x4){0.f, 0.f, 0.f, 0.f};

  issue(0, 0);
  issue(1, 1);
  for (int ck = 0; ck < 8; ++ck) {
    const int bufi = ck % 3;
    if (ck + 2 < 8) issue(ck + 2, (ck + 2) % 3);
    if (ck + 2 < 8)      asm volatile("s_waitcnt vmcnt(4)" ::: "memory");
    else if (ck + 1 < 8) asm volatile("s_waitcnt vmcnt(2)" ::: "memory");
    else                 asm volatile("s_waitcnt vmcnt(0)" ::: "memory");
    __builtin_amdgcn_s_barrier();         // whole tile ck is now in LDS
    __builtin_amdgcn_sched_barrier(0);
    const char* xb = &lx[bufi * 8192] + n * 512;
#pragma unroll
    for (int kk = 0; kk < 4; ++kk) {
      const int c1 = kk * 8 + quad * 2;
      const f32x4 xa = *(const f32x4*)(xb + ((c1 ^ n) << 4));
      const f32x4 xc = *(const f32x4*)(xb + (((c1 + 1) ^ n) << 4));
      const f16x8 af = cvt8(xa, xc);
      const f16* wq = wl + (size_t)(ck * 4 + kk) * 512;
      const f16x8 w0 = *(const f16x8*)(wq);
      const f16x8 w1 = *(const f16x8*)(wq + 16384);
      const f16x8 w2 = *(const f16x8*)(wq + 32768);
      acc[0] = MFMA32(af, w0, acc[0]);
      acc[1] = MFMA32(af, w1, acc[1]);
      acc[2] = MFMA32(af, w2, acc[2]);
    }
    __builtin_amdgcn_s_barrier();         // reads done before buf refill
  }

  // epilogue: bias + final layouts (q*QSCALE, k swizzled, v tiles)
  const int r0 = rowbase + quad * 4;
#pragma unroll
  for (int i2 = 0; i2 < 3; ++i2) {
    const int mt = mtb + i2;
    const int mat = mt >> 2, tile = mt & 3;
    const int d = tile * 16 + n;  // d&15 == n
    const f32x4 aa = acc[i2];
    if (mat == 0) {
      const float bi = bq[d];
#pragma unroll
      for (int r = 0; r < 4; ++r)
        qs[(size_t)(r0 + r) * DDIM + d] = (f16)((aa[r] + bi) * QSCALE);
    } else if (mat == 1) {
      const float bi = bk[d];
#pragma unroll
      for (int r = 0; r < 4; ++r) {
        const int tt = r0 + r;
        const int col = ((((d >> 3) ^ (tt & 7)) << 3) | (d & 7));
        ks[(size_t)tt * DDIM + col] = (f16)(aa[r] + bi);
      }
    } else {
      const float bi = bv[d];
      const int bb = r0 >> 12;
      const int tl = r0 & (SEQ - 1);
      const int ck2 = tl >> 6;
      const int bsw = (((tl & 63) >> 2) ^ n) << 2;
      *(f16x4*)(vc + ((size_t)(bb * 64 + ck2) * 64 + d) * 64 + bsw) =
          cvt4(aa[0] + bi, aa[1] + bi, aa[2] + bi, aa[3] + bi);
    }
  }
}

// ---------------- flash attention: round-7 skeleton + coalesced pacc ---------
// Round-10 post-mortem: G=4 neutral (4th dead micro-structure theory). Round-9
// profile held the real lead: WRITE_SIZE 59 MB / FETCH 24 MB per attn dispatch
// vs ~18/7 expected -- 3.3x write amplification from the pacc store pattern
// (8B f16x4 per lane at 128B row stride -> 32B dirty per cache line + RMW
// fetches). ~60 MB spurious HBM/iter ~= 9-12 us of attn's 30. Fix: tile-major
// pacc layout -- within each 16-row tile, element (row,col) at
// t*256 + n*16 + quad*4 + r (t=col>>4) -> each wave (g,t) store is one
// contiguous 512 B block. combine reads the matching swizzle. Arithmetic
// untouched => absmax bit-identical. Everything else = round 7 exactly.
template <int NSPLIT>
__global__ __launch_bounds__(256, 3) void attn_kernel(const f16* __restrict__ qs,
                                                      const f16* __restrict__ ks,
                                                      const f16* __restrict__ vc,
                                                      float* __restrict__ outp,
                                                      f16* __restrict__ pacc,
                                                      float* __restrict__ pm,
                                                      float* __restrict__ pl) {
  __shared__ __attribute__((aligned(16))) f16 lk[3 * 4096];  // [buf][key][64 d swz]
  __shared__ __attribute__((aligned(16))) f16 lv[3 * 4096];  // [buf][d][64 key swz]
  const int tid = threadIdx.x, lane = tid & 63, w = tid >> 6;
  const int n = lane & 15, quad = lane >> 4;
  const int split = blockIdx.x % NSPLIT;
  const int rowblk = blockIdx.x / NSPLIT;
  const int row0 = rowblk * 128 + w * 32;
  const int bb = row0 >> 12;
  const int kbase = split * (SEQ / NSPLIT);
  const int kc0 = kbase >> 6;
  const int NC = SEQ / NSPLIT / 64;

  const f16* ksb = ks + (size_t)bb * SEQ * DDIM;
  const f16* vcb = vc + (size_t)bb * 64 * 4096;

  auto issue = [&](int c, int bufi) {
#pragma unroll
    for (int i = 0; i < 2; ++i) {
      const int id = 2 * w + i;
      GLDS(ksb + (size_t)(kbase + c * 64) * 64 + id * 512 + lane * 8,
           &lk[bufi * 4096 + id * 512]);
      GLDS(vcb + (size_t)(kc0 + c) * 4096 + id * 512 + lane * 8,
           &lv[bufi * 4096 + id * 512]);
    }
  };

  // persistent Q B-fragments (16x16x32): B[k=d=quad*8+j][col=q=n]
  f16x8 qf[2][2];
#pragma unroll
  for (int g = 0; g < 2; ++g)
#pragma unroll
    for (int hh = 0; hh < 2; ++hh)
      qf[g][hh] = *(const f16x8*)(qs + (size_t)(row0 + g * 16 + n) * DDIM + hh * 32 + quad * 8);

  // swizzle read offsets (per-lane constants)
  const int kswz = (quad ^ (n & 7)) << 3;          // klo block; khi = kswz ^ 32
  int vswz[4];
#pragma unroll
  for (int st = 0; st < 4; ++st) vswz[st] = ((((st << 2) | quad) ^ n) << 2);

  f32x4 acc[2][4];
  float m[2] = {-1e30f, -1e30f}, ll[2] = {0.f, 0.f};
#pragma unroll
  for (int g = 0; g < 2; ++g)
#pragma unroll
    for (int t = 0; t < 4; ++t) acc[g][t] = (f32x4){0.f, 0.f, 0.f, 0.f};

  issue(0, 0);
  issue(1, 1);
  for (int c = 0; c < NC; ++c) {
    const int bufi = c % 3;
    if (c + 2 < NC) issue(c + 2, (c + 2) % 3);
    // wait for THIS chunk's 4 GLDS only; newer chunks stay in flight
    if (c + 2 < NC)      asm volatile("s_waitcnt vmcnt(8)" ::: "memory");
    else if (c + 1 < NC) asm volatile("s_waitcnt vmcnt(4)" ::: "memory");
    else                 asm volatile("s_waitcnt vmcnt(0)" ::: "memory");
    __builtin_amdgcn_s_barrier();         // whole K/V tile c is now in LDS
    __builtin_amdgcn_sched_barrier(0);

    // S' = K·Q^T
    f32x4 s[2][4];
#pragma unroll
    for (int st = 0; st < 4; ++st) {
      const f16* lkr = &lk[bufi * 4096 + (st * 16 + n) * 64];
      const f16x8 klo = *(const f16x8*)(lkr + kswz);
      const f16x8 khi = *(const f16x8*)(lkr + (kswz ^ 32));
#pragma unroll
      for (int g = 0; g < 2; ++g) {
        f32x4 z = (f32x4){0.f, 0.f, 0.f, 0.f};
        z = MFMA32(klo, qf[g][0], z);
        s[g][st] = MFMA32(khi, qf[g][1], z);
      }
    }

    // per-lane online softmax; P packed directly as 16x16x16 B-fragments
    f16x4 pq[2][4];
#pragma unroll
    for (int g = 0; g < 2; ++g) {
      f32x4 mx;
#pragma unroll
      for (int r = 0; r < 4; ++r)
        mx[r] = fmaxf(fmaxf(s[g][0][r], s[g][1][r]), fmaxf(s[g][2][r], s[g][3][r]));
      float mloc = fmaxf(fmaxf(mx[0], mx[1]), fmaxf(mx[2], mx[3]));
      mloc = fmaxf(mloc, __shfl_xor(mloc, 16));
      mloc = fmaxf(mloc, __shfl_xor(mloc, 32));
      const float mnew = fmaxf(m[g], mloc);
      const float alpha = __builtin_amdgcn_exp2f(m[g] - mnew);
      m[g] = mnew;
      float psum = 0.f;
#pragma unroll
      for (int st = 0; st < 4; ++st) {
        f32x4 p;
#pragma unroll
        for (int r = 0; r < 4; ++r) p[r] = __builtin_amdgcn_exp2f(s[g][st][r] - mnew);
        psum += (p[0] + p[1]) + (p[2] + p[3]);
        pq[g][st] = cvt4(p[0], p[1], p[2], p[3]);
      }
      ll[g] = ll[g] * alpha + psum;
#pragma unroll
      for (int t = 0; t < 4; ++t) acc[g][t] *= alpha;
    }

    // O^T += V^T·P^T : A = V^T frag [m=d][k=key quad*4+j] (swizzled LDS read)
#pragma unroll
    for (int dt = 0; dt < 4; ++dt) {
      const f16* lvr = &lv[bufi * 4096 + (dt * 16 + n) * 64];
#pragma unroll
      for (int st = 0; st < 4; ++st) {
        const f16x4 va = *(const f16x4*)(lvr + vswz[st]);
        acc[0][dt] = MFMA16(va, pq[0][st], acc[0][dt]);
        acc[1][dt] = MFMA16(va, pq[1][st], acc[1][dt]);
      }
    }
    __builtin_amdgcn_s_barrier();         // reads done before buf refill
  }

  float lred[2];
#pragma unroll
  for (int g = 0; g < 2; ++g) {
    float l = ll[g];
    l += __shfl_xor(l, 16);
    l += __shfl_xor(l, 32);
    lred[g] = l;
  }

  if (NSPLIT == 1) {
#pragma unroll
    for (int g = 0; g < 2; ++g) {
      const float inv = 1.0f / lred[g];
      const int q = row0 + g * 16 + n;
#pragma unroll
      for (int t = 0; t < 4; ++t) {
        f32x4 o = acc[g][t];
#pragma unroll
        for (int r = 0; r < 4; ++r) o[r] *= inv;
        *(f32x4*)(outp + (size_t)q * DDIM + t * 16 + quad * 4) = o;
      }
    }
  } else {
    // coalesced tile-major pacc: tile = 16 rows; elem (row,col) at
    // t*256 + n*16 + quad*4 + r  ->  wave store per (g,t) = 512 B contiguous
#pragma unroll
    for (int g = 0; g < 2; ++g) {
      const int q0 = row0 + g * 16;     // 16-aligned tile base
      f16* pb = pacc + (size_t)split * SEG + ((size_t)q0 << 6) + n * 16 + quad * 4;
#pragma unroll
      for (int t = 0; t < 4; ++t)
        *(f16x4*)(pb + t * 256) =
            cvt4(acc[g][t][0], acc[g][t][1], acc[g][t][2], acc[g][t][3]);
      if (quad == 0) {
        pm[split * NROW + q0 + n] = m[g];
        pl[split * NROW + q0 + n] = lred[g];
      }
    }
  }
}

// ---------------- attn split-K combine (tile-major f16 partials) -------------
template <int NSPLIT>
__global__ __launch_bounds__(256) void combine_kernel(const f16* __restrict__ pacc,
                                                      const float* __restrict__ pm,
                                                      const float* __restrict__ pl,
                                                      float* __restrict__ out) {
  const int idx = blockIdx.x * 256 + threadIdx.x;  // NROW*16 units
  const int row = idx >> 4;
  const int c = (idx & 15) * 4;
  // tile-major offset: ((row&~15)<<6) + (c>>4)*256 + (row&15)*16 + (c&15)
  const size_t off = ((size_t)(row & ~15) << 6) + ((size_t)(c >> 4) << 8) +
                     ((row & 15) << 4) + (c & 15);
  float mm = pm[row];
#pragma unroll
  for (int s = 1; s < NSPLIT; ++s) mm = fmaxf(mm, pm[s * NROW + row]);
  float L = 0.f;
  f32x4 o = (f32x4){0.f, 0.f, 0.f, 0.f};
#pragma unroll
  for (int s = 0; s < NSPLIT; ++s) {
    const float e = __builtin_amdgcn_exp2f(pm[s * NROW + row] - mm);
    L += pl[s * NROW + row] * e;
    const f16x4 a = *(const f16x4*)(pacc + (size_t)s * SEG + off);
#pragma unroll
    for (int j = 0; j < 4; ++j) o[j] += (float)a[j] * e;
  }
  const float inv = 1.0f / L;
#pragma unroll
  for (int j = 0; j < 4; ++j) o[j] *= inv;
  *(f32x4*)(out + (size_t)row * DDIM + c) = o;
}

extern "C" void kernel_launch(void* const* d_in, const int* in_sizes, int n_in,
                              void* d_out, int out_size, void* d_ws, size_t ws_size,
                              hipStream_t stream) {
  const float* x  = (const float*)d_in[0];
  const float* Wq = (const float*)d_in[1];
  const float* bq = (const float*)d_in[2];
  const float* Wk = (const float*)d_in[3];
  const float* bk = (const float*)d_in[4];
  const float* Wv = (const float*)d_in[5];
  const float* bv = (const float*)d_in[6];
  float* out = (float*)d_out;

  f16* wf2 = (f16*)d_ws;                      // 3*64*1024 f16, mt-major slots
  f16* qs = wf2 + 3 * 65536;
  f16* ks = qs + (size_t)SEG;                 // block-swizzled
  f16* vc = ks + (size_t)SEG;                 // chunk-major tiles, swizzled
  f16* pacc = vc + (size_t)SEG;               // [NSPL][SEG] tile-major partials
  float* pm = (float*)(pacc + (size_t)NSPL * SEG);
  float* pl = pm + (size_t)NSPL * NROW;
  const size_t need = (size_t)((char*)(pl + (size_t)NSPL * NROW) - (char*)d_ws);

  prep_w_kernel<<<dim3(96), dim3(256), 0, stream>>>(Wq, Wk, Wv, wf2);
  proj_kernel<<<dim3(NROW / 16), dim3(256), 0, stream>>>(x, wf2, bq, bk, bv, qs, ks, vc);

  if (ws_size >= need) {
    attn_kernel<NSPL><<<dim3(128 * NSPL), dim3(256), 0, stream>>>(qs, ks, vc, nullptr, pacc, pm, pl);
    combine_kernel<NSPL><<<dim3(NROW * 16 / 256), dim3(256), 0, stream>>>(pacc, pm, pl, out);
  } else {
    attn_kernel<1><<<dim3(128), dim3(256), 0, stream>>>(qs, ks, vc, out, nullptr, nullptr, nullptr);
  }
}